// Round 2
// baseline (2908.139 us; speedup 1.0000x reference)
//
#include <hip/hip_runtime.h>
#include <hip/hip_bf16.h>

// VectorQuantizer forward, MI355X.
// z: [32,128,32,32] fp32, codebook: [2048,128] fp32.
// Outputs (flat fp32, concatenated):
//   loss(1), zq_ste(4194304), perplexity(1), onehot_img(67108864),
//   idx_img(32768), index_hist(65536), softmax_hist(65536),
//   commitment(1), quantization(1), softmax_loss(1)  => 71467013 total.

#define K_NUM 2048
#define D_NUM 128
#define B_NUM 32
#define HW_NUM 1024
#define N_NUM 32768

// out offsets (in floats)
#define O_LOSS   0ull
#define O_ZQ     1ull
#define O_PERP   4194305ull
#define O_ONEHOT 4194306ull
#define O_IDX    71303170ull
#define O_IHIST  71335938ull
#define O_SHIST  71401474ull
#define O_COMMIT 71467010ull
#define O_QUANT  71467011ull
#define O_SM     71467012ull

// ws offsets (bytes)
#define WS_IDX    0ull        // 32768 * 4 (int idx per position)
#define WS_SCAL   131072ull   // 2 floats: sum(min_dist), sum(log l)
#define WS_ET     131328ull   // 32*2048*4 floats = 1 MiB, layout [dc][k][4] = -2*e
#define WS_CNORM  1179904ull  // 2048 * 4  (||e_k||^2)
#define WS_HIST   1188096ull  // 1024*2048*4 = 8 MiB per-block softmax-hist partials
#define WS_END    9576704ull

// ---------------------------------------------------------------------------
// K1: eTi[dc][k][0..3] = -2*codebook[k][dc*4..dc*4+3]; cnorm[k] = ||e_k||^2.
// grid 32 x 256.
__global__ void vq_prep(const float* __restrict__ cb, float* __restrict__ eTi,
                        float* __restrict__ cnorm) {
    int k = blockIdx.x * 64 + (threadIdx.x >> 2);
    int q = threadIdx.x & 3;  // dim quarter
    float s = 0.f;
#pragma unroll
    for (int i = 0; i < 8; ++i) {
        int d = q * 32 + i * 4;
        int dc = d >> 2;
        float4 v = *reinterpret_cast<const float4*>(cb + (size_t)k * D_NUM + d);
        s += v.x * v.x + v.y * v.y + v.z * v.z + v.w * v.w;
        float4 w = {-2.f * v.x, -2.f * v.y, -2.f * v.z, -2.f * v.w};
        *reinterpret_cast<float4*>(eTi + ((size_t)dc * K_NUM + k) * 4) = w;
    }
    s += __shfl_xor(s, 1, 64);
    s += __shfl_xor(s, 2, 64);
    if (q == 0) cnorm[k] = s;
}

// ---------------------------------------------------------------------------
// K2: fused distances + argmin + softmax stats + hists. grid 1024 x 512.
// Block owns 32 consecutive positions (one b). Wave w owns positions w*4..w*4+3.
// Lane owns codes k = lane + 64*j, j=0..31 -> acc[4][32] in VGPRs.
// dist = ||z||^2 + ||e||^2 + dot(z, -2e); the -2 is folded into eTi.
template <bool WSH>
__global__ __launch_bounds__(512, 4) void vq_main(
    const float* __restrict__ z, const float* __restrict__ eTi,
    const float* __restrict__ cnorm, float* __restrict__ out,
    int* __restrict__ idx_ws, float* __restrict__ scal,
    float* __restrict__ wsh) {
    __shared__ __align__(16) float zt[32][D_NUM];  // 16 KB [pos][d]
    __shared__ __align__(16) float et[8192];       // 32 KB: chunk dc, [k][4]
    __shared__ float hist[K_NUM];                  // 8 KB block softmax hist
    __shared__ float cn[K_NUM];                    // 8 KB ||e||^2
    __shared__ float ssum[8], slog[8];

    const int tid = threadIdx.x;
    const int lane = tid & 63;
    const int wv = tid >> 6;
    const int n0 = blockIdx.x * 32;
    const int b = blockIdx.x >> 5;       // 32 blocks per batch element
    const int hw0 = (blockIdx.x & 31) * 32;

    for (int i = tid; i < K_NUM; i += 512) {
        hist[i] = 0.f;
        cn[i] = cnorm[i];
    }

    // stage z tile: z[b][d][hw0+pos] -> zt[pos][d]
    const float* zb = z + (size_t)b * (D_NUM * HW_NUM) + hw0;
    for (int i = tid; i < 1024; i += 512) {
        int d = i >> 3;
        int q = i & 7;
        float4 v = *reinterpret_cast<const float4*>(zb + d * HW_NUM + q * 4);
        zt[q * 4 + 0][d] = v.x;
        zt[q * 4 + 1][d] = v.y;
        zt[q * 4 + 2][d] = v.z;
        zt[q * 4 + 3][d] = v.w;
    }
    __syncthreads();

    // ||z||^2 for this wave's 4 positions (butterfly over 64 lanes)
    float znorm[4];
#pragma unroll
    for (int p = 0; p < 4; ++p) {
        int pg = wv * 4 + p;
        float a = zt[pg][lane];
        float c2 = zt[pg][lane + 64];
        float s = a * a + c2 * c2;
        for (int off = 32; off; off >>= 1) s += __shfl_xor(s, off, 64);
        znorm[p] = s;
    }

    float acc[4][32];
#pragma unroll
    for (int p = 0; p < 4; ++p)
#pragma unroll
        for (int j = 0; j < 32; ++j) acc[p][j] = 0.f;

    const float4* e4 = reinterpret_cast<const float4*>(et);
    // main matmul: 32 chunks of 4 dims; one ds_read_b128 per code per chunk
    for (int dc = 0; dc < 32; ++dc) {
        const float4* src = reinterpret_cast<const float4*>(eTi + (size_t)dc * 8192);
#pragma unroll
        for (int it = 0; it < 4; ++it) {
            int idx = it * 512 + tid;
            reinterpret_cast<float4*>(et)[idx] = src[idx];
        }
        __syncthreads();
        float4 z4[4];
#pragma unroll
        for (int p = 0; p < 4; ++p)
            z4[p] = *reinterpret_cast<const float4*>(&zt[wv * 4 + p][dc * 4]);
#pragma unroll 8
        for (int j = 0; j < 32; ++j) {
            float4 e = e4[lane + 64 * j];
#pragma unroll
            for (int p = 0; p < 4; ++p) {
                acc[p][j] = fmaf(z4[p].x, e.x, acc[p][j]);
                acc[p][j] = fmaf(z4[p].y, e.y, acc[p][j]);
                acc[p][j] = fmaf(z4[p].z, e.z, acc[p][j]);
                acc[p][j] = fmaf(z4[p].w, e.w, acc[p][j]);
            }
        }
        __syncthreads();
    }

    // dist = znorm + cnorm + dot'
#pragma unroll
    for (int j = 0; j < 32; ++j) {
        float c = cn[lane + 64 * j];
#pragma unroll
        for (int p = 0; p < 4; ++p) acc[p][j] += znorm[p] + c;
    }

    // per-position min / argmin / sum-exp
    float m[4], l[4];
    int bk[4];
#pragma unroll
    for (int p = 0; p < 4; ++p) {
        float mv = acc[p][0];
        int mi = lane;
#pragma unroll
        for (int j = 1; j < 32; ++j) {
            int kk = lane + 64 * j;
            if (acc[p][j] < mv) { mv = acc[p][j]; mi = kk; }
        }
        for (int off = 32; off; off >>= 1) {
            float ov = __shfl_xor(mv, off, 64);
            int oi = __shfl_xor(mi, off, 64);
            if (ov < mv || (ov == mv && oi < mi)) { mv = ov; mi = oi; }
        }
        m[p] = mv;
        bk[p] = mi;

        float s = 0.f;
#pragma unroll
        for (int j = 0; j < 32; ++j) s += __expf(mv - acc[p][j]);
        for (int off = 32; off; off >>= 1) s += __shfl_xor(s, off, 64);
        l[p] = s;
    }

    // block softmax hist: lane's 4 positions per code, LDS atomic across waves
    float rinv[4];
#pragma unroll
    for (int p = 0; p < 4; ++p) rinv[p] = 1.f / l[p];
#pragma unroll
    for (int j = 0; j < 32; ++j) {
        float h = 0.f;
#pragma unroll
        for (int p = 0; p < 4; ++p) h += __expf(m[p] - acc[p][j]) * rinv[p];
        atomicAdd(&hist[lane + 64 * j], h);
    }

    if (lane == 0) {
        float summ = 0.f, suml = 0.f;
#pragma unroll
        for (int p = 0; p < 4; ++p) {
            int n = n0 + wv * 4 + p;
            idx_ws[n] = bk[p];
            out[O_IDX + n] = (float)bk[p];
            atomicAdd(&out[O_IHIST + (size_t)b * K_NUM + bk[p]], 1.0f);
            summ += m[p];
            suml += __logf(l[p]);
        }
        ssum[wv] = summ;
        slog[wv] = suml;
    }
    __syncthreads();
    if (tid == 0) {
        float a = 0.f, g = 0.f;
#pragma unroll
        for (int w = 0; w < 8; ++w) { a += ssum[w]; g += slog[w]; }
        atomicAdd(&scal[0], a);
        atomicAdd(&scal[1], g);
    }
    if (WSH) {
        for (int i = tid; i < K_NUM; i += 512)
            wsh[(size_t)blockIdx.x * K_NUM + i] = hist[i];
    } else {
        for (int i = tid; i < K_NUM; i += 512)
            atomicAdd(&out[O_SHIST + (size_t)b * K_NUM + i], hist[i]);
    }
}

// ---------------------------------------------------------------------------
// K3: softmax_hist reduce: out[b][k] = sum over 32 sub-blocks. grid 256 x 256.
__global__ void vq_hist(const float* __restrict__ wsh, float* __restrict__ out) {
    int gid = blockIdx.x * 256 + threadIdx.x;  // 0..65535 = b*2048 + k
    int b = gid >> 11;
    int k = gid & 2047;
    const float* p = wsh + (size_t)b * 32 * K_NUM + k;
    float s = 0.f;
#pragma unroll
    for (int sb = 0; sb < 32; ++sb) s += p[(size_t)sb * K_NUM];
    out[O_SHIST + gid] = s;
}

// ---------------------------------------------------------------------------
// K4: scatter ones into memset-zeroed onehot_img. grid 128 x 256.
__global__ void vq_scatter(const int* __restrict__ idx, float* __restrict__ out) {
    int n = blockIdx.x * 256 + threadIdx.x;  // 0..32767
    int b = n >> 10;
    int hw = n & 1023;
    int k = idx[n];
    out[O_ONEHOT + (((size_t)b * K_NUM + k) << 10) + hw] = 1.0f;
}

// ---------------------------------------------------------------------------
// K5: zq gather: out_zq[b][c][hw] = codebook[idx[b][hw]][c]. grid 512 x 256.
__global__ void vq_zq(const int* __restrict__ idx,
                      const float* __restrict__ cb, float* __restrict__ out) {
    __shared__ int sidx[64];
    __shared__ float lcb[64][129];  // +1 pad: conflict-free column reads
    int t = threadIdx.x;
    int b = blockIdx.x >> 4;
    int hw0 = (blockIdx.x & 15) * 64;
    if (t < 64) sidx[t] = idx[b * HW_NUM + hw0 + t];
    __syncthreads();
    for (int i = t; i < 2048; i += 256) {  // stage 64 gathered codebook rows
        int row = i >> 5;
        int col = (i & 31) * 4;
        float4 v = *reinterpret_cast<const float4*>(cb + (size_t)sidx[row] * D_NUM + col);
        lcb[row][col + 0] = v.x;
        lcb[row][col + 1] = v.y;
        lcb[row][col + 2] = v.z;
        lcb[row][col + 3] = v.w;
    }
    __syncthreads();
    int hwl = t & 63;
    int c0 = t >> 6;
#pragma unroll
    for (int cc = 0; cc < 32; ++cc) {
        int c = cc * 4 + c0;
        out[O_ZQ + (((size_t)b * D_NUM + c) << 10) + hw0 + hwl] = lcb[hwl][c];
    }
}

// ---------------------------------------------------------------------------
// K6: scalars + perplexity. grid 1 x 256.
__global__ void vq_finalize(float* __restrict__ out, const float* __restrict__ scal) {
    __shared__ float red[256];
    int t = threadIdx.x;
    float ent = 0.f;
    for (int k = t; k < K_NUM; k += 256) {
        float c = 0.f;
#pragma unroll
        for (int b = 0; b < B_NUM; ++b) c += out[O_IHIST + (size_t)b * K_NUM + k];
        float p = c * (1.f / 32768.f);
        ent += p * __logf(p + 1e-10f);
    }
    red[t] = ent;
    __syncthreads();
    for (int s = 128; s; s >>= 1) {
        if (t < s) red[t] += red[t + s];
        __syncthreads();
    }
    if (t == 0) {
        float mse = scal[0] * (1.f / (32768.f * 128.f));  // fwd: quant == commit
        out[O_LOSS] = 1.25f * mse;                        // q + 0.25*c + 0*sm
        out[O_PERP] = __expf(-red[0]);
        out[O_COMMIT] = mse;
        out[O_QUANT] = mse;
        out[O_SM] = scal[1] * (1.f / 32768.f);            // mean log(sum exp(m-d))
    }
}

// ---------------------------------------------------------------------------
extern "C" void kernel_launch(void* const* d_in, const int* in_sizes, int n_in,
                              void* d_out, int out_size, void* d_ws, size_t ws_size,
                              hipStream_t stream) {
    const float* z = (const float*)d_in[0];
    const float* cb = (const float*)d_in[1];
    float* out = (float*)d_out;
    char* ws = (char*)d_ws;

    int* idx_ws = (int*)(ws + WS_IDX);
    float* scal = (float*)(ws + WS_SCAL);
    float* eTi = (float*)(ws + WS_ET);
    float* cnorm = (float*)(ws + WS_CNORM);
    float* wsh = (float*)(ws + WS_HIST);
    const bool big = ws_size >= WS_END;

    // zero accumulators + the onehot plane (ws/d_out are poisoned pre-launch)
    hipMemsetAsync(scal, 0, 2 * sizeof(float), stream);
    hipMemsetAsync(out + O_IHIST, 0, 2 * B_NUM * K_NUM * sizeof(float), stream);
    hipMemsetAsync(out + O_ONEHOT, 0, (size_t)B_NUM * K_NUM * HW_NUM * sizeof(float),
                   stream);

    vq_prep<<<32, 256, 0, stream>>>(cb, eTi, cnorm);
    if (big)
        vq_main<true><<<1024, 512, 0, stream>>>(z, eTi, cnorm, out, idx_ws, scal, wsh);
    else
        vq_main<false><<<1024, 512, 0, stream>>>(z, eTi, cnorm, out, idx_ws, scal, wsh);
    vq_scatter<<<128, 256, 0, stream>>>(idx_ws, out);
    vq_zq<<<512, 256, 0, stream>>>(idx_ws, cb, out);
    if (big) vq_hist<<<256, 256, 0, stream>>>(wsh, out);
    vq_finalize<<<1, 256, 0, stream>>>(out, scal);
}

// Round 4
// 808.355 us; speedup vs baseline: 3.5976x; 3.5976x over previous
//
#include <hip/hip_runtime.h>
#include <hip/hip_bf16.h>

// VectorQuantizer forward, MI355X.
// z: [32,128,32,32] fp32, codebook: [2048,128] fp32.
// Outputs (flat fp32, concatenated):
//   loss(1), zq_ste(4194304), perplexity(1), onehot_img(67108864),
//   idx_img(32768), index_hist(65536), softmax_hist(65536),
//   commitment(1), quantization(1), softmax_loss(1)  => 71467013 total.
//
// R3 = R2 resubmitted unchanged (broker timeout; spill fix never measured).

#define K_NUM 2048
#define D_NUM 128
#define B_NUM 32
#define HW_NUM 1024
#define N_NUM 32768

// out offsets (in floats)
#define O_LOSS   0ull
#define O_ZQ     1ull
#define O_PERP   4194305ull
#define O_ONEHOT 4194306ull
#define O_IDX    71303170ull
#define O_IHIST  71335938ull
#define O_SHIST  71401474ull
#define O_COMMIT 71467010ull
#define O_QUANT  71467011ull
#define O_SM     71467012ull

// ws offsets (bytes)
#define WS_IDX    0ull        // 32768 * 4 (int idx per position)
#define WS_SCAL   131072ull   // 2 floats: sum(min_dist), sum(log l)
#define WS_ET     131328ull   // 32*2048*4 floats = 1 MiB, layout [dc][k][4] = -2*e
#define WS_CNORM  1179904ull  // 2048 * 4  (||e_k||^2)
#define WS_HIST   1188096ull  // 1024*2048*4 = 8 MiB per-block softmax-hist partials
#define WS_END    9576704ull

// ---------------------------------------------------------------------------
// K1: eTi[dc][k][0..3] = -2*codebook[k][dc*4..dc*4+3]; cnorm[k] = ||e_k||^2.
// grid 32 x 256.
__global__ void vq_prep(const float* __restrict__ cb, float* __restrict__ eTi,
                        float* __restrict__ cnorm) {
    int k = blockIdx.x * 64 + (threadIdx.x >> 2);
    int q = threadIdx.x & 3;  // dim quarter
    float s = 0.f;
#pragma unroll
    for (int i = 0; i < 8; ++i) {
        int d = q * 32 + i * 4;
        int dc = d >> 2;
        float4 v = *reinterpret_cast<const float4*>(cb + (size_t)k * D_NUM + d);
        s += v.x * v.x + v.y * v.y + v.z * v.z + v.w * v.w;
        float4 w = {-2.f * v.x, -2.f * v.y, -2.f * v.z, -2.f * v.w};
        *reinterpret_cast<float4*>(eTi + ((size_t)dc * K_NUM + k) * 4) = w;
    }
    s += __shfl_xor(s, 1, 64);
    s += __shfl_xor(s, 2, 64);
    if (q == 0) cnorm[k] = s;
}

// ---------------------------------------------------------------------------
// K2: fused distances + argmin + softmax stats + hists. grid 1024 x 512.
// Block owns 32 consecutive positions (one b). Wave w owns positions w*4..w*4+3.
// Lane owns codes k = lane + 64*j, j=0..31 -> acc[4][32] in VGPRs.
// dist = ||z||^2 + ||e||^2 + dot(z, -2e); the -2 is folded into eTi.
//
// NOTE (R2 post-mortem): acc[4][32] = 128 VGPRs/thread. Rule #20: every acc
// access must be compile-time-indexed -> FULL unroll on the j-loop (partial
// unroll made j runtime -> 17 GB of scratch traffic, VALUBusy 8%).
// __launch_bounds__ 2nd arg must stay 2 (256-VGPR budget); 4 caps at 128
// VGPRs and guarantees spill.
template <bool WSH>
__global__ __launch_bounds__(512, 2) void vq_main(
    const float* __restrict__ z, const float* __restrict__ eTi,
    const float* __restrict__ cnorm, float* __restrict__ out,
    int* __restrict__ idx_ws, float* __restrict__ scal,
    float* __restrict__ wsh) {
    __shared__ __align__(16) float zt[32][D_NUM];  // 16 KB [pos][d]
    __shared__ __align__(16) float et[8192];       // 32 KB: chunk dc, [k][4]
    __shared__ float hist[K_NUM];                  // 8 KB block softmax hist
    __shared__ float cn[K_NUM];                    // 8 KB ||e||^2
    __shared__ float ssum[8], slog[8];

    const int tid = threadIdx.x;
    const int lane = tid & 63;
    const int wv = tid >> 6;
    const int n0 = blockIdx.x * 32;
    const int b = blockIdx.x >> 5;       // 32 blocks per batch element
    const int hw0 = (blockIdx.x & 31) * 32;

    for (int i = tid; i < K_NUM; i += 512) {
        hist[i] = 0.f;
        cn[i] = cnorm[i];
    }

    // stage z tile: z[b][d][hw0+pos] -> zt[pos][d]
    const float* zb = z + (size_t)b * (D_NUM * HW_NUM) + hw0;
    for (int i = tid; i < 1024; i += 512) {
        int d = i >> 3;
        int q = i & 7;
        float4 v = *reinterpret_cast<const float4*>(zb + d * HW_NUM + q * 4);
        zt[q * 4 + 0][d] = v.x;
        zt[q * 4 + 1][d] = v.y;
        zt[q * 4 + 2][d] = v.z;
        zt[q * 4 + 3][d] = v.w;
    }
    __syncthreads();

    // ||z||^2 for this wave's 4 positions (butterfly over 64 lanes)
    float znorm[4];
#pragma unroll
    for (int p = 0; p < 4; ++p) {
        int pg = wv * 4 + p;
        float a = zt[pg][lane];
        float c2 = zt[pg][lane + 64];
        float s = a * a + c2 * c2;
        for (int off = 32; off; off >>= 1) s += __shfl_xor(s, off, 64);
        znorm[p] = s;
    }

    float acc[4][32];
#pragma unroll
    for (int p = 0; p < 4; ++p)
#pragma unroll
        for (int j = 0; j < 32; ++j) acc[p][j] = 0.f;

    const float4* e4 = reinterpret_cast<const float4*>(et);
    // main matmul: 32 chunks of 4 dims; one ds_read_b128 per code per chunk
    for (int dc = 0; dc < 32; ++dc) {
        const float4* src = reinterpret_cast<const float4*>(eTi + (size_t)dc * 8192);
#pragma unroll
        for (int it = 0; it < 4; ++it) {
            int idx = it * 512 + tid;
            reinterpret_cast<float4*>(et)[idx] = src[idx];
        }
        __syncthreads();
        float4 z4[4];
#pragma unroll
        for (int p = 0; p < 4; ++p)
            z4[p] = *reinterpret_cast<const float4*>(&zt[wv * 4 + p][dc * 4]);
#pragma unroll
        for (int j = 0; j < 32; ++j) {
            float4 e = e4[lane + 64 * j];
#pragma unroll
            for (int p = 0; p < 4; ++p) {
                acc[p][j] = fmaf(z4[p].x, e.x, acc[p][j]);
                acc[p][j] = fmaf(z4[p].y, e.y, acc[p][j]);
                acc[p][j] = fmaf(z4[p].z, e.z, acc[p][j]);
                acc[p][j] = fmaf(z4[p].w, e.w, acc[p][j]);
            }
        }
        __syncthreads();
    }

    // dist = znorm + cnorm + dot'
#pragma unroll
    for (int j = 0; j < 32; ++j) {
        float c = cn[lane + 64 * j];
#pragma unroll
        for (int p = 0; p < 4; ++p) acc[p][j] += znorm[p] + c;
    }

    // per-position min / argmin / sum-exp
    float m[4], l[4];
    int bk[4];
#pragma unroll
    for (int p = 0; p < 4; ++p) {
        float mv = acc[p][0];
        int mi = lane;
#pragma unroll
        for (int j = 1; j < 32; ++j) {
            int kk = lane + 64 * j;
            if (acc[p][j] < mv) { mv = acc[p][j]; mi = kk; }
        }
        for (int off = 32; off; off >>= 1) {
            float ov = __shfl_xor(mv, off, 64);
            int oi = __shfl_xor(mi, off, 64);
            if (ov < mv || (ov == mv && oi < mi)) { mv = ov; mi = oi; }
        }
        m[p] = mv;
        bk[p] = mi;

        float s = 0.f;
#pragma unroll
        for (int j = 0; j < 32; ++j) s += __expf(mv - acc[p][j]);
        for (int off = 32; off; off >>= 1) s += __shfl_xor(s, off, 64);
        l[p] = s;
    }

    // block softmax hist: lane's 4 positions per code, LDS atomic across waves
    float rinv[4];
#pragma unroll
    for (int p = 0; p < 4; ++p) rinv[p] = 1.f / l[p];
#pragma unroll
    for (int j = 0; j < 32; ++j) {
        float h = 0.f;
#pragma unroll
        for (int p = 0; p < 4; ++p) h += __expf(m[p] - acc[p][j]) * rinv[p];
        atomicAdd(&hist[lane + 64 * j], h);
    }

    if (lane == 0) {
        float summ = 0.f, suml = 0.f;
#pragma unroll
        for (int p = 0; p < 4; ++p) {
            int n = n0 + wv * 4 + p;
            idx_ws[n] = bk[p];
            out[O_IDX + n] = (float)bk[p];
            atomicAdd(&out[O_IHIST + (size_t)b * K_NUM + bk[p]], 1.0f);
            summ += m[p];
            suml += __logf(l[p]);
        }
        ssum[wv] = summ;
        slog[wv] = suml;
    }
    __syncthreads();
    if (tid == 0) {
        float a = 0.f, g = 0.f;
#pragma unroll
        for (int w = 0; w < 8; ++w) { a += ssum[w]; g += slog[w]; }
        atomicAdd(&scal[0], a);
        atomicAdd(&scal[1], g);
    }
    if (WSH) {
        for (int i = tid; i < K_NUM; i += 512)
            wsh[(size_t)blockIdx.x * K_NUM + i] = hist[i];
    } else {
        for (int i = tid; i < K_NUM; i += 512)
            atomicAdd(&out[O_SHIST + (size_t)b * K_NUM + i], hist[i]);
    }
}

// ---------------------------------------------------------------------------
// K3: softmax_hist reduce: out[b][k] = sum over 32 sub-blocks. grid 256 x 256.
__global__ void vq_hist(const float* __restrict__ wsh, float* __restrict__ out) {
    int gid = blockIdx.x * 256 + threadIdx.x;  // 0..65535 = b*2048 + k
    int b = gid >> 11;
    int k = gid & 2047;
    const float* p = wsh + (size_t)b * 32 * K_NUM + k;
    float s = 0.f;
#pragma unroll
    for (int sb = 0; sb < 32; ++sb) s += p[(size_t)sb * K_NUM];
    out[O_SHIST + gid] = s;
}

// ---------------------------------------------------------------------------
// K4: scatter ones into memset-zeroed onehot_img. grid 128 x 256.
__global__ void vq_scatter(const int* __restrict__ idx, float* __restrict__ out) {
    int n = blockIdx.x * 256 + threadIdx.x;  // 0..32767
    int b = n >> 10;
    int hw = n & 1023;
    int k = idx[n];
    out[O_ONEHOT + (((size_t)b * K_NUM + k) << 10) + hw] = 1.0f;
}

// ---------------------------------------------------------------------------
// K5: zq gather: out_zq[b][c][hw] = codebook[idx[b][hw]][c]. grid 512 x 256.
__global__ void vq_zq(const int* __restrict__ idx,
                      const float* __restrict__ cb, float* __restrict__ out) {
    __shared__ int sidx[64];
    __shared__ float lcb[64][129];  // +1 pad: conflict-free column reads
    int t = threadIdx.x;
    int b = blockIdx.x >> 4;
    int hw0 = (blockIdx.x & 15) * 64;
    if (t < 64) sidx[t] = idx[b * HW_NUM + hw0 + t];
    __syncthreads();
    for (int i = t; i < 2048; i += 256) {  // stage 64 gathered codebook rows
        int row = i >> 5;
        int col = (i & 31) * 4;
        float4 v = *reinterpret_cast<const float4*>(cb + (size_t)sidx[row] * D_NUM + col);
        lcb[row][col + 0] = v.x;
        lcb[row][col + 1] = v.y;
        lcb[row][col + 2] = v.z;
        lcb[row][col + 3] = v.w;
    }
    __syncthreads();
    int hwl = t & 63;
    int c0 = t >> 6;
#pragma unroll
    for (int cc = 0; cc < 32; ++cc) {
        int c = cc * 4 + c0;
        out[O_ZQ + (((size_t)b * D_NUM + c) << 10) + hw0 + hwl] = lcb[hwl][c];
    }
}

// ---------------------------------------------------------------------------
// K6: scalars + perplexity. grid 1 x 256.
__global__ void vq_finalize(float* __restrict__ out, const float* __restrict__ scal) {
    __shared__ float red[256];
    int t = threadIdx.x;
    float ent = 0.f;
    for (int k = t; k < K_NUM; k += 256) {
        float c = 0.f;
#pragma unroll
        for (int b = 0; b < B_NUM; ++b) c += out[O_IHIST + (size_t)b * K_NUM + k];
        float p = c * (1.f / 32768.f);
        ent += p * __logf(p + 1e-10f);
    }
    red[t] = ent;
    __syncthreads();
    for (int s = 128; s; s >>= 1) {
        if (t < s) red[t] += red[t + s];
        __syncthreads();
    }
    if (t == 0) {
        float mse = scal[0] * (1.f / (32768.f * 128.f));  // fwd: quant == commit
        out[O_LOSS] = 1.25f * mse;                        // q + 0.25*c + 0*sm
        out[O_PERP] = __expf(-red[0]);
        out[O_COMMIT] = mse;
        out[O_QUANT] = mse;
        out[O_SM] = scal[1] * (1.f / 32768.f);            // mean log(sum exp(m-d))
    }
}

// ---------------------------------------------------------------------------
extern "C" void kernel_launch(void* const* d_in, const int* in_sizes, int n_in,
                              void* d_out, int out_size, void* d_ws, size_t ws_size,
                              hipStream_t stream) {
    const float* z = (const float*)d_in[0];
    const float* cb = (const float*)d_in[1];
    float* out = (float*)d_out;
    char* ws = (char*)d_ws;

    int* idx_ws = (int*)(ws + WS_IDX);
    float* scal = (float*)(ws + WS_SCAL);
    float* eTi = (float*)(ws + WS_ET);
    float* cnorm = (float*)(ws + WS_CNORM);
    float* wsh = (float*)(ws + WS_HIST);
    const bool big = ws_size >= WS_END;

    // zero accumulators + the onehot plane (ws/d_out are poisoned pre-launch)
    hipMemsetAsync(scal, 0, 2 * sizeof(float), stream);
    hipMemsetAsync(out + O_IHIST, 0, 2 * B_NUM * K_NUM * sizeof(float), stream);
    hipMemsetAsync(out + O_ONEHOT, 0, (size_t)B_NUM * K_NUM * HW_NUM * sizeof(float),
                   stream);

    vq_prep<<<32, 256, 0, stream>>>(cb, eTi, cnorm);
    if (big)
        vq_main<true><<<1024, 512, 0, stream>>>(z, eTi, cnorm, out, idx_ws, scal, wsh);
    else
        vq_main<false><<<1024, 512, 0, stream>>>(z, eTi, cnorm, out, idx_ws, scal, wsh);
    vq_scatter<<<128, 256, 0, stream>>>(idx_ws, out);
    vq_zq<<<512, 256, 0, stream>>>(idx_ws, cb, out);
    if (big) vq_hist<<<256, 256, 0, stream>>>(wsh, out);
    vq_finalize<<<1, 256, 0, stream>>>(out, scal);
}